// Round 3
// baseline (98.353 us; speedup 1.0000x reference)
//
#include <hip/hip_runtime.h>

// Outputs concatenated flat (fp32):
//   [0, 4L)            input_tensor [L,4] = {x,y,z,onehot}
//   [4L, 4L+3B)        closest_points [B,3]
//   [4L+3B, 4L+4B)     min_index [B] (as float)
// B = 128, L = 1e6 (derived at launch).

#define NRECV 128
#define TILE 512
#define BLK 512
#define NWAVE (BLK / 64)
#define CELL_STRIDE 16  // u64 units: 128B per cell -> atomics on distinct lines

typedef unsigned long long u64;

__global__ __launch_bounds__(128) void k_init(u64* __restrict__ cells, int n) {
  int i = blockIdx.x * 128 + threadIdx.x;
  if (i < n) cells[i] = ~0ull;
}

// Main: grid-stride over point tiles. Per tile:
//  - stage 512 points to LDS as float4{x,y,z,0}; fused write of out[L,4]
//  - each lane: 4 receivers {c, c+32, c+64, c+96}, c = tid&31; the two
//    half-waves take adjacent points p2, p2+1 (2-way LDS broadcast = free)
//  - per-block merge (shfl + LDS), then one atomicMin(u64 key) per receiver
//    into a padded cell. Key = d2bits<<32 | idx: exact lowest-index tiebreak.
__global__ __launch_bounds__(BLK) void k_main(
    const float* __restrict__ pts, const float* __restrict__ recv,
    u64* __restrict__ cells, int nbanks, float* __restrict__ out,
    int L, int ntiles) {
  __shared__ float4 sp4[TILE + 1];
  __shared__ u64 sm[NWAVE][NRECV];

  const int tid = threadIdx.x;
  const int g = tid >> 6;          // wave id: points p2 == 2g (mod 2*NWAVE)
  const int c = tid & 31;          // receiver base
  const int ph = (tid >> 5) & 1;   // half-wave point offset

  float rx[4], ry[4], rz[4];
#pragma unroll
  for (int k = 0; k < 4; ++k) {
    rx[k] = recv[(c + 32 * k) * 3 + 0];
    ry[k] = recv[(c + 32 * k) * 3 + 1];
    rz[k] = recv[(c + 32 * k) * 3 + 2];
  }

  float bd[4] = {1e30f, 1e30f, 1e30f, 1e30f};
  int bi[4] = {0, 0, 0, 0};

  for (int t = blockIdx.x; t < ntiles; t += gridDim.x) {
    const int base = t * TILE;
    const int cnt = min(TILE, L - base);

    if (tid < cnt) {
      const int gi = base + tid;
      float4 v;
      v.x = pts[3 * gi + 0];
      v.y = pts[3 * gi + 1];
      v.z = pts[3 * gi + 2];
      v.w = 0.0f;
      sp4[tid] = v;
      reinterpret_cast<float4*>(out)[gi] = v;  // fused [L,4] fill
    }
    if (tid == 0 && cnt < TILE)  // pad so p2+1 is safe when cnt is odd
      sp4[cnt] = make_float4(1e30f, 1e30f, 1e30f, 0.0f);
    __syncthreads();

#pragma unroll 2
    for (int p2 = 2 * g; p2 < cnt; p2 += 2 * NWAVE) {
      const int p = p2 + ph;
      const float4 q = sp4[p];
#pragma unroll
      for (int k = 0; k < 4; ++k) {
        const float dx = q.x - rx[k];
        const float dy = q.y - ry[k];
        const float dz = q.z - rz[k];
        const float d = fmaf(dz, dz, fmaf(dy, dy, dx * dx));
        const bool cc = d < bd[k];  // strict < + increasing p => lowest idx
        bd[k] = cc ? d : bd[k];
        bi[k] = cc ? (base + p) : bi[k];
      }
    }
    __syncthreads();
  }

  // d2 >= 0 -> float bits are order-monotone; u64 min == (d2, lowest idx) min.
  u64 key[4];
#pragma unroll
  for (int k = 0; k < 4; ++k) {
    key[k] = ((u64)__float_as_uint(bd[k]) << 32) | (unsigned int)bi[k];
    const u64 o = __shfl_xor(key[k], 32, 64);  // merge the two half-waves
    key[k] = o < key[k] ? o : key[k];
  }
  if (ph == 0) {
#pragma unroll
    for (int k = 0; k < 4; ++k) sm[g][c + 32 * k] = key[k];
  }
  __syncthreads();
  if (tid < NRECV) {
    u64 best = sm[0][tid];
#pragma unroll
    for (int w = 1; w < NWAVE; ++w) {
      const u64 o = sm[w][tid];
      best = o < best ? o : best;
    }
    const int bank = blockIdx.x & (nbanks - 1);
    atomicMin(&cells[(size_t)(bank * NRECV + tid) * CELL_STRIDE], best);
  }
}

__global__ __launch_bounds__(128) void k_finalize(
    const u64* __restrict__ cells, int nbanks,
    const float* __restrict__ pts, float* __restrict__ out, int L) {
  const int r = threadIdx.x;  // 1 block, 128 threads
  u64 best = ~0ull;
  for (int b = 0; b < nbanks; ++b) {
    const u64 o = cells[(size_t)(b * NRECV + r) * CELL_STRIDE];
    best = o < best ? o : best;
  }
  const unsigned int idx = (unsigned int)(best & 0xffffffffu);
  const size_t Lo = (size_t)L * 4;
  out[Lo + (size_t)r * 3 + 0] = pts[(size_t)idx * 3 + 0];
  out[Lo + (size_t)r * 3 + 1] = pts[(size_t)idx * 3 + 1];
  out[Lo + (size_t)r * 3 + 2] = pts[(size_t)idx * 3 + 2];
  out[Lo + (size_t)NRECV * 3 + r] = (float)idx;  // min_index as float
  out[(size_t)idx * 4 + 3] = 1.0f;               // one-hot (benign race)
  if (r == 0) out[3] = 1.0f;  // reference quirk: B>1 also sets index 0
}

extern "C" void kernel_launch(void* const* d_in, const int* in_sizes, int n_in,
                              void* d_out, int out_size, void* d_ws, size_t ws_size,
                              hipStream_t stream) {
  const float* pts = (const float*)d_in[0];   // [L,3]
  const float* recv = (const float*)d_in[1];  // [128,3]
  float* out = (float*)d_out;
  u64* cells = (u64*)d_ws;

  const int L = in_sizes[0] / 3;
  const int ntiles = (L + TILE - 1) / TILE;

  // 4 padded banks if ws allows (64KB), else 1 (16KB). Power of 2.
  const int nbanks =
      (ws_size >= (size_t)4 * NRECV * CELL_STRIDE * sizeof(u64)) ? 4 : 1;
  const int ncell_u64 = nbanks * NRECV * CELL_STRIDE;

  int grid = 512;
  if (grid > ntiles) grid = ntiles;

  k_init<<<(ncell_u64 + 127) / 128, 128, 0, stream>>>(cells, ncell_u64);
  k_main<<<grid, BLK, 0, stream>>>(pts, recv, cells, nbanks, out, L, ntiles);
  k_finalize<<<1, 128, 0, stream>>>(cells, nbanks, pts, out, L);
}

// Round 4
// 98.232 us; speedup vs baseline: 1.0012x; 1.0012x over previous
//
#include <hip/hip_runtime.h>

// Outputs concatenated flat (fp32):
//   [0, 4L)            input_tensor [L,4] = {x,y,z,onehot}
//   [4L, 4L+3B)        closest_points [B,3]
//   [4L+3B, 4L+4B)     min_index [B] (as float)
// B = 128, L = 1e6 (derived at launch).

#define NRECV 128
#define TILE 512
#define BLK 512
#define NWAVE (BLK / 64)
#define GRID_MAX 1024

typedef unsigned long long u64;
typedef float f4 __attribute__((ext_vector_type(4)));

// Stage 1: grid-stride over point tiles.
//  - stage 512 points to LDS as {x,y,z,0}; fused non-temporal write of out[L,4]
//  - lane c = tid&31 owns receivers {c, c+32, c+64, c+96}; half-waves take
//    adjacent points p, p+1 (2 distinct LDS addrs per b128 read = free)
//  - per-block merge (shfl + LDS) -> stage[block][recv], no atomics.
//  Key = d2bits<<32 | idx: d2 >= 0 so float bits are order-monotone; u64 min
//  == (min d2, then lowest index) — exact reference tie-break.
__global__ __launch_bounds__(BLK) void k_main(
    const float* __restrict__ pts, const float* __restrict__ recv,
    u64* __restrict__ stage, float* __restrict__ out, int L, int ntiles) {
  __shared__ f4 sp4[TILE + 1];
  __shared__ u64 sm[NWAVE][NRECV];

  const int tid = threadIdx.x;
  const int g = tid >> 6;         // wave id: point-pairs p2 == 2g (mod 16)
  const int c = tid & 31;         // receiver base lane
  const int ph = (tid >> 5) & 1;  // half-wave point offset

  float rx[4], ry[4], rz[4];
#pragma unroll
  for (int k = 0; k < 4; ++k) {
    rx[k] = recv[(c + 32 * k) * 3 + 0];
    ry[k] = recv[(c + 32 * k) * 3 + 1];
    rz[k] = recv[(c + 32 * k) * 3 + 2];
  }

  float bd[4] = {1e30f, 1e30f, 1e30f, 1e30f};
  int bi[4] = {0, 0, 0, 0};

  for (int t = blockIdx.x; t < ntiles; t += gridDim.x) {
    const int base = t * TILE;
    const int cnt = min(TILE, L - base);

    if (tid < cnt) {
      const int gi = base + tid;
      f4 v;
      v.x = pts[3 * gi + 0];
      v.y = pts[3 * gi + 1];
      v.z = pts[3 * gi + 2];
      v.w = 0.0f;
      sp4[tid] = v;
      __builtin_nontemporal_store(v, reinterpret_cast<f4*>(out) + gi);
    }
    if (tid == 0 && cnt < TILE) {  // pad so p+1 read is safe
      f4 pad;
      pad.x = 1e30f; pad.y = 1e30f; pad.z = 1e30f; pad.w = 0.0f;
      sp4[cnt] = pad;
    }
    __syncthreads();

#pragma unroll 4
    for (int p2 = 2 * g; p2 < cnt; p2 += 2 * NWAVE) {
      const int p = p2 + ph;
      const f4 q = sp4[p];
#pragma unroll
      for (int k = 0; k < 4; ++k) {
        const float dx = q.x - rx[k];
        const float dy = q.y - ry[k];
        const float dz = q.z - rz[k];
        const float d = fmaf(dz, dz, fmaf(dy, dy, dx * dx));
        const bool cc = d < bd[k];  // strict < + increasing p => lowest idx
        bd[k] = cc ? d : bd[k];
        bi[k] = cc ? (base + p) : bi[k];
      }
    }
    __syncthreads();
  }

  u64 key[4];
#pragma unroll
  for (int k = 0; k < 4; ++k) {
    key[k] = ((u64)__float_as_uint(bd[k]) << 32) | (unsigned int)bi[k];
    const u64 o = __shfl_xor(key[k], 32, 64);  // merge half-waves
    key[k] = o < key[k] ? o : key[k];
  }
  if (ph == 0) {
#pragma unroll
    for (int k = 0; k < 4; ++k) sm[g][c + 32 * k] = key[k];
  }
  __syncthreads();
  if (tid < NRECV) {
    u64 best = sm[0][tid];
#pragma unroll
    for (int w = 1; w < NWAVE; ++w) {
      const u64 o = sm[w][tid];
      best = o < best ? o : best;
    }
    stage[(size_t)blockIdx.x * NRECV + tid] = best;
  }
}

// Stage 2: one 64-thread block per receiver; reduce per-block bests, emit
// outputs, scatter one-hot (stage-1 zeroed the column; stream order).
__global__ __launch_bounds__(64) void k_finalize(
    const u64* __restrict__ stage, int nblocks,
    const float* __restrict__ pts, float* __restrict__ out, int L) {
  const int r = blockIdx.x;
  const int tid = threadIdx.x;

  u64 best = ~0ull;
  for (int j = tid; j < nblocks; j += 64) {
    const u64 k = stage[(size_t)j * NRECV + r];
    best = k < best ? k : best;
  }
#pragma unroll
  for (int off = 32; off > 0; off >>= 1) {
    const u64 o = __shfl_down(best, off);
    best = o < best ? o : best;
  }
  if (tid == 0) {
    const unsigned int idx = (unsigned int)(best & 0xffffffffu);
    const size_t Lo = (size_t)L * 4;
    out[Lo + (size_t)r * 3 + 0] = pts[(size_t)idx * 3 + 0];
    out[Lo + (size_t)r * 3 + 1] = pts[(size_t)idx * 3 + 1];
    out[Lo + (size_t)r * 3 + 2] = pts[(size_t)idx * 3 + 2];
    out[Lo + (size_t)NRECV * 3 + r] = (float)idx;  // min_index as float
    out[(size_t)idx * 4 + 3] = 1.0f;               // one-hot (benign race)
    if (r == 0) out[3] = 1.0f;  // reference quirk: B>1 also sets index 0
  }
}

extern "C" void kernel_launch(void* const* d_in, const int* in_sizes, int n_in,
                              void* d_out, int out_size, void* d_ws, size_t ws_size,
                              hipStream_t stream) {
  const float* pts = (const float*)d_in[0];   // [L,3]
  const float* recv = (const float*)d_in[1];  // [128,3]
  float* out = (float*)d_out;
  u64* stage = (u64*)d_ws;

  const int L = in_sizes[0] / 3;
  const int ntiles = (L + TILE - 1) / TILE;

  int grid = GRID_MAX;
  if (grid > ntiles) grid = ntiles;
  const size_t need = (size_t)grid * NRECV * sizeof(u64);
  if (need > ws_size) {
    grid = (int)(ws_size / (NRECV * sizeof(u64)));
    if (grid < 1) grid = 1;
  }

  k_main<<<grid, BLK, 0, stream>>>(pts, recv, stage, out, L, ntiles);
  k_finalize<<<NRECV, 64, 0, stream>>>(stage, grid, pts, out, L);
}